// Round 7
// baseline (276.548 us; speedup 1.0000x reference)
//
#include <hip/hip_runtime.h>
#include <hip/hip_bf16.h>
#include <hip/hip_fp16.h>

// GCN: h1 = relu(GCNConv(x,W1,b1)); h2 = GCNConv(h1,W2,b2);
//      h3 = relu(h2@Wm1+bm1); out = h3@Wm2+bm2
// R2: CSR-by-dst gather-reduce replaced scatter atomics (10x write amp).
// R4: 2-pass XCD-local bucket sort. R5: dinv folded into GEMM epilogue.
// R6/R8 FAILED: multi-phase LDS GEMM fusion -> spills. R7: fp16 g-tables.
// R9: 2-node/wave aggregate, 8-deep (255.8us). R13 FAILED: 4-deep (263us).
// R14: cleanup (253.7us). R15 FAILED (1071us): scatter-side LDS agg.
// R16 FAILED (268.5us): perm pairing + csr-128 (bundled; perm blamed).
// R17 NEUTRAL (252.2us): depth 16. R18 WIN (249.0us): per-row 64x64 GEMM
//      fused into aggregate epilogues (agg 53.7us; issue-bound, no pipe sat).
// R19 FAILED (272.9us): b64 dual-row gathers -> 6.4M LDS conflicts.
// R20 FAILED (269.5us): uint4 wide-lane gathers; conflicts ~0, vmem 4x down,
//      yet agg 63us / VALU 61%. TA-issue model dead: gather-loop restructures
//      never pay (R13/R17/R19/R20). R18 gather loop is the local optimum.
// R21: (a) agg_fused reverted to R18 verbatim. (b) csr at 128-node buckets
//      WITHOUT perm (tests R16's attribution; 782 blocks x 9KB LDS vs 196 x
//      36.5KB sub-occupancy). (c) MLP tail fused into agg2 epilogue: h3 row
//      staged in LDS, matvec vs Wm2t[40][65] (stride-65 = conflict-free),
//      writes out directly. Kills gemm<40> dispatch + 51MB hA round-trip.

namespace {

constexpr int N_NODES = 100000;
constexpr int N_EDGES = 1000000;
constexpr int BN = 128;                         // dst nodes per bucket
constexpr int NBUCK = (N_NODES + BN - 1) / BN;  // 782 buckets
constexpr int CAP_RAW = 2048;   // raw edges/bucket (mean 1280, sd ~36)
constexpr int CAP_COL = 2560;   // pad-16 edges/bucket (mean ~2112)
constexpr int EPB_A = 2048;     // edges per passA block

// passA: partition edges into NBUCK buckets by dst>>7. word=(src<<7)|(dst&127)
// (17+7=24 bits). Per-block int32/int64 detection: sample 512 odd words of own
// range (int64 high halves are all 0; int32 node ids ~surely not).
__global__ __launch_bounds__(256) void bucket_kernel(const void* __restrict__ ei,
                                                     int* __restrict__ bucketCnt,
                                                     unsigned* __restrict__ tmp) {
  __shared__ int hist[NBUCK];
  __shared__ int basePB[NBUCK];
  __shared__ int cur[NBUCK];
  __shared__ int sflag;
  int t = threadIdx.x;
  for (int i = t; i < NBUCK; i += 256) { hist[i] = 0; cur[i] = 0; }
  if (t == 0) sflag = 0;
  __syncthreads();

  int e0 = blockIdx.x * EPB_A;
  const unsigned* w = (const unsigned*)ei;
  unsigned any = 0;
#pragma unroll
  for (int s = 0; s < 2; s++) {
    int e = e0 + s * 256 + t;
    if (e < N_EDGES) any |= w[2 * e + 1];
  }
  if (any) sflag = 1;  // benign race, all writers store 1
  __syncthreads();
  int is32 = sflag;

  unsigned wreg[8];
  int breg[8];
#pragma unroll
  for (int k = 0; k < 8; k++) {
    int e = e0 + k * 256 + t;
    breg[k] = -1;
    if (e < N_EDGES) {
      int s, d;
      if (is32) {
        const int* p = (const int*)ei;
        s = p[e]; d = p[N_EDGES + e];
      } else {
        const long long* p = (const long long*)ei;
        s = (int)p[e]; d = (int)p[N_EDGES + e];
      }
      wreg[k] = ((unsigned)s << 7) | (unsigned)(d & 127);
      breg[k] = d >> 7;
      atomicAdd(&hist[breg[k]], 1);
    }
  }
  __syncthreads();
  for (int i = t; i < NBUCK; i += 256)
    basePB[i] = hist[i] ? atomicAdd(&bucketCnt[i], hist[i]) : 0;
  __syncthreads();
#pragma unroll
  for (int k = 0; k < 8; k++) {
    if (breg[k] >= 0) {
      int r = atomicAdd(&cur[breg[k]], 1);
      tmp[(size_t)breg[k] * CAP_RAW + basePB[breg[k]] + r] = wreg[k];
    }
  }
}

// passB: one block per 128-node bucket, 256 thr, ~9KB LDS (782 blocks -> full
// machine vs old 196 x 36.5KB at 0.77 blocks/CU). LDS counting sort; rows
// padded to mult 16 with sentinel N_NODES (zero row); emit row_start/row_end
// + dinv. NO perm (R16's regression attributed to perm, not bucket size).
__global__ __launch_bounds__(256) void csr_kernel(const unsigned* __restrict__ tmp,
                                                  const int* __restrict__ bucketCnt,
                                                  int* __restrict__ col,
                                                  int* __restrict__ row_start,
                                                  int* __restrict__ row_end,
                                                  float* __restrict__ dinv) {
  __shared__ int sc[BN];
  __shared__ int hist[BN];
  __shared__ unsigned stage[CAP_RAW];
  int b = blockIdx.x, t = threadIdx.x;
  int myCnt = bucketCnt[b];
  int baseC = b * CAP_COL;
  size_t baseT = (size_t)b * CAP_RAW;
  int nb = min(BN, N_NODES - b * BN);

  if (t < BN) hist[t] = 0;
  __syncthreads();
  for (int i = t; i < myCnt; i += 256) {
    unsigned w = tmp[baseT + i];
    stage[i] = w;
    atomicAdd(&hist[w & 127u], 1);
  }
  __syncthreads();

  int deg = (t < BN) ? hist[t] : 0;
  int pdeg = (deg + 15) & ~15;  // pad rows to mult 16 (16-deep pipeline)
  if (t < BN) sc[t] = pdeg;
  __syncthreads();
  for (int off = 1; off < BN; off <<= 1) {
    int u = (t >= off && t < BN) ? sc[t - off] : 0;
    __syncthreads();
    if (t < BN) sc[t] += u;
    __syncthreads();
  }
  int pexcl = (t < BN) ? sc[t] - pdeg : 0;
  int d = b * BN + t;
  if (t < nb) {
    row_start[d] = baseC + pexcl;
    row_end[d] = baseC + pexcl + pdeg;
    dinv[d] = rsqrtf((float)deg + 1.0f);
  }
  __syncthreads();
  if (t < BN) hist[t] = pexcl;  // reuse as scatter cursor
  __syncthreads();
  for (int i = t; i < myCnt; i += 256) {
    unsigned w = stage[i];
    int pos = atomicAdd(&hist[w & 127u], 1);
    col[baseC + pos] = (int)(w >> 7);
  }
  if (t < nb)
    for (int j = deg; j < pdeg; j++) col[baseC + pexcl + j] = N_NODES;
}

__device__ inline uint4 pack_half8(const float* v) {
  __half2 h0 = __floats2half2_rn(v[0], v[1]);
  __half2 h1 = __floats2half2_rn(v[2], v[3]);
  __half2 h2 = __floats2half2_rn(v[4], v[5]);
  __half2 h3 = __floats2half2_rn(v[6], v[7]);
  uint4 u;
  u.x = *(unsigned*)&h0; u.y = *(unsigned*)&h1;
  u.z = *(unsigned*)&h2; u.w = *(unsigned*)&h3;
  return u;
}

// g[r] = (op(A[r])@W) * dinv[r], fp16 out, zero pad row N_NODES.
// 128 rows/block, 256 thr, thread = 4 rows x 8 cols. W staged in LDS.
__global__ __launch_bounds__(256) void gemm_g_kernel(const float* __restrict__ A,
                                                     const float* __restrict__ W,
                                                     const float* __restrict__ dinv,
                                                     __half* __restrict__ g,
                                                     __half* __restrict__ gpad2,
                                                     int reluIn) {
  __shared__ float Ws[64 * 64];
  int t = threadIdx.x;
  if (blockIdx.x == 0 && t < 32) {
    ((float*)(g + (size_t)N_NODES * 64))[t] = 0.f;  // pad row (this table)
    if (gpad2) ((float*)(gpad2 + (size_t)N_NODES * 64))[t] = 0.f;  // pad row (agg1 output table)
  }
  for (int i = t; i < 64 * 64 / 4; i += 256) ((float4*)Ws)[i] = ((const float4*)W)[i];
  __syncthreads();

  int rg = t >> 3, cg = t & 7;
  int r0 = blockIdx.x * 128 + rg * 4;
  int c0 = cg * 8;

  float acc[4][8];
#pragma unroll
  for (int i = 0; i < 4; i++)
#pragma unroll
    for (int j = 0; j < 8; j++) acc[i][j] = 0.f;

  const float4* A4 = (const float4*)A;
  for (int kk = 0; kk < 16; kk++) {
    float4 a[4];
#pragma unroll
    for (int i = 0; i < 4; i++) {
      int r = r0 + i;
      float4 v = (r < N_NODES) ? A4[(size_t)r * 16 + kk] : make_float4(0.f, 0.f, 0.f, 0.f);
      if (reluIn) {
        v.x = fmaxf(v.x, 0.f); v.y = fmaxf(v.y, 0.f);
        v.z = fmaxf(v.z, 0.f); v.w = fmaxf(v.w, 0.f);
      }
      a[i] = v;
    }
#pragma unroll
    for (int q = 0; q < 4; q++) {
      int k = kk * 4 + q;
      float w[8];
#pragma unroll
      for (int j = 0; j < 2; j++) *(float4*)&w[4 * j] = *(const float4*)&Ws[k * 64 + c0 + 4 * j];
#pragma unroll
      for (int i = 0; i < 4; i++) {
        float av = q == 0 ? a[i].x : q == 1 ? a[i].y : q == 2 ? a[i].z : a[i].w;
#pragma unroll
        for (int j = 0; j < 8; j++) acc[i][j] = fmaf(av, w[j], acc[i][j]);
      }
    }
  }
#pragma unroll
  for (int i = 0; i < 4; i++) {
    int r = r0 + i;
    if (r < N_NODES) {
      float s = dinv[r];
#pragma unroll
      for (int j = 0; j < 8; j++) acc[i][j] *= s;
      *(uint4*)(g + (size_t)r * 64 + c0) = pack_half8(acc[i]);
    }
  }
}

// Fused gather-aggregate + per-row GEMM epilogue (R18 structure, verbatim
// gather; R21 adds MODE-2 MLP-tail fusion).
// Gather: 2 nodes/wave (lanes 0-31 node d0, 32-63 node d1); lane covers 2
// feats as one half2 gather (one instr fetches TWO 128B rows); 16-deep
// pipeline; sentinel pad rows hit the L1-hot zero row.
// Epilogue: row h = dinv*(self+sum)+bconv staged in per-half-wave LDS slot
// (wave-synchronous); lane computes cols {2sub, 2sub+1} = h @ W from
// Ws[64*64] (b64 reads, 2-way alias = free; h reads broadcast).
// MODE 1 (conv1 -> conv2 g-table): relu(h) pre-GEMM, *dinv post, fp16 out.
// MODE 2 (conv2 -> final out): h3 = relu(h@Wm1+bm1) restaged in the same row
//      slot, then out[d][0..39] = h3 @ Wm2 + bm2 via Wm2t[40][65] (stride-65
//      = conflict-free b128), written directly to d_out. No hA round-trip.
template <int MODE>
__global__ __launch_bounds__(256) void agg_fused(const __half* __restrict__ g,
                                                 const int* __restrict__ col,
                                                 const int* __restrict__ row_start,
                                                 const int* __restrict__ row_end,
                                                 const float* __restrict__ dinv,
                                                 const float* __restrict__ bconv,
                                                 const float* __restrict__ W,
                                                 const float* __restrict__ bpost,
                                                 const float* __restrict__ Wm2,
                                                 const float* __restrict__ bm2,
                                                 void* __restrict__ outp) {
  __shared__ float Ws[64 * 64];   // 16 KB
  __shared__ float rows[8][64];   // 2 KB, one row slot per half-wave
  __shared__ float Wm2t[(MODE == 2) ? 40 : 1][65];  // transposed tail weights
  int t = threadIdx.x;
  for (int i = t; i < 64 * 64 / 4; i += 256) ((float4*)Ws)[i] = ((const float4*)W)[i];
  if (MODE == 2) {
    for (int i = t; i < 64 * 40; i += 256) {
      int k = i / 40, c = i % 40;
      Wm2t[c][k] = Wm2[i];
    }
  }
  __syncthreads();

  int wave = t >> 6;
  int lane = t & 63;
  int half = lane >> 5;
  int sub = lane & 31;
  int slot = t >> 5;  // half-wave id 0..7
  int d = blockIdx.x * 8 + wave * 2 + half;

  const __half2* g2 = (const __half2*)g;
  int e0 = row_start[d];
  int len = row_end[d] - e0;

  float2 a0 = __half22float2(g2[(size_t)d * 32 + sub]);  // self (dinv in g)
  float2 a1 = {0.f, 0.f}, a2 = {0.f, 0.f}, a3 = {0.f, 0.f};
  float2 a4 = {0.f, 0.f}, a5 = {0.f, 0.f}, a6 = {0.f, 0.f}, a7 = {0.f, 0.f};

  for (int i = 0; i < len; i += 16) {  // per-half-wave trip count (exec-mask divergence)
    int4 ca = *(const int4*)(col + e0 + i);
    int4 cb = *(const int4*)(col + e0 + i + 4);
    int4 cc = *(const int4*)(col + e0 + i + 8);
    int4 cd = *(const int4*)(col + e0 + i + 12);
    float2 h0 = __half22float2(g2[(size_t)ca.x * 32 + sub]);
    float2 h1 = __half22float2(g2[(size_t)ca.y * 32 + sub]);
    float2 h2 = __half22float2(g2[(size_t)ca.z * 32 + sub]);
    float2 h3 = __half22float2(g2[(size_t)ca.w * 32 + sub]);
    float2 h4 = __half22float2(g2[(size_t)cb.x * 32 + sub]);
    float2 h5 = __half22float2(g2[(size_t)cb.y * 32 + sub]);
    float2 h6 = __half22float2(g2[(size_t)cb.z * 32 + sub]);
    float2 h7 = __half22float2(g2[(size_t)cb.w * 32 + sub]);
    float2 h8 = __half22float2(g2[(size_t)cc.x * 32 + sub]);
    float2 h9 = __half22float2(g2[(size_t)cc.y * 32 + sub]);
    float2 hA = __half22float2(g2[(size_t)cc.z * 32 + sub]);
    float2 hB = __half22float2(g2[(size_t)cc.w * 32 + sub]);
    float2 hC = __half22float2(g2[(size_t)cd.x * 32 + sub]);
    float2 hD = __half22float2(g2[(size_t)cd.y * 32 + sub]);
    float2 hE = __half22float2(g2[(size_t)cd.z * 32 + sub]);
    float2 hF = __half22float2(g2[(size_t)cd.w * 32 + sub]);
    a0.x += h0.x; a0.y += h0.y; a1.x += h1.x; a1.y += h1.y;
    a2.x += h2.x; a2.y += h2.y; a3.x += h3.x; a3.y += h3.y;
    a4.x += h4.x; a4.y += h4.y; a5.x += h5.x; a5.y += h5.y;
    a6.x += h6.x; a6.y += h6.y; a7.x += h7.x; a7.y += h7.y;
    a0.x += h8.x; a0.y += h8.y; a1.x += h9.x; a1.y += h9.y;
    a2.x += hA.x; a2.y += hA.y; a3.x += hB.x; a3.y += hB.y;
    a4.x += hC.x; a4.y += hC.y; a5.x += hD.x; a5.y += hD.y;
    a6.x += hE.x; a6.y += hE.y; a7.x += hF.x; a7.y += hF.y;
  }
  float rx = ((a0.x + a1.x) + (a2.x + a3.x)) + ((a4.x + a5.x) + (a6.x + a7.x));
  float ry = ((a0.y + a1.y) + (a2.y + a3.y)) + ((a4.y + a5.y) + (a6.y + a7.y));
  float dv = dinv[d];
  float2 bv = ((const float2*)bconv)[sub];
  float hx = fmaf(rx, dv, bv.x);
  float hy = fmaf(ry, dv, bv.y);
  if (MODE == 1) { hx = fmaxf(hx, 0.f); hy = fmaxf(hy, 0.f); }

  // stage row in this half-wave's slot; wave-synchronous (single-instruction
  // write covers all lanes, subsequent reads ordered by lgkmcnt)
  *(float2*)&rows[slot][2 * sub] = make_float2(hx, hy);

  float o0 = 0.f, o1 = 0.f;
#pragma unroll 8
  for (int ks = 0; ks < 32; ks++) {
    float2 hv = *(const float2*)&rows[slot][2 * ks];           // broadcast
    float2 w0 = *(const float2*)&Ws[(2 * ks) * 64 + 2 * sub];  // 2-way bank (free)
    float2 w1 = *(const float2*)&Ws[(2 * ks + 1) * 64 + 2 * sub];
    o0 = fmaf(hv.x, w0.x, o0);
    o0 = fmaf(hv.y, w1.x, o0);
    o1 = fmaf(hv.x, w0.y, o1);
    o1 = fmaf(hv.y, w1.y, o1);
  }

  if (MODE == 1) {
    o0 *= dv; o1 *= dv;
    __half2 hh = __floats2half2_rn(o0, o1);
    ((__half2*)outp)[(size_t)d * 32 + sub] = hh;
  } else {
    // h3 = relu(h2@Wm1 + bm1), cols 2sub, 2sub+1
    float2 bp = ((const float2*)bpost)[sub];
    float h3a = fmaxf(o0 + bp.x, 0.f);
    float h3b = fmaxf(o1 + bp.y, 0.f);
    // restage h3 into the same slot (matvec1 reads are complete in program
    // order for this wave; slot is owned by this half-wave)
    *(float2*)&rows[slot][2 * sub] = make_float2(h3a, h3b);

    // tail matvec: out[d][c] = h3 . Wm2t[c] + bm2[c]; c0=sub, c1=sub+32(<40)
    float p0 = 0.f, p1 = 0.f;
    int c1 = sub + 32;
#pragma unroll 4
    for (int k4 = 0; k4 < 64; k4 += 4) {
      float4 hv = *(const float4*)&rows[slot][k4];  // broadcast
      float4 wa = *(const float4*)&Wm2t[sub][k4];   // stride 65 -> 32 banks
      p0 = fmaf(hv.x, wa.x, p0); p0 = fmaf(hv.y, wa.y, p0);
      p0 = fmaf(hv.z, wa.z, p0); p0 = fmaf(hv.w, wa.w, p0);
      if (sub < 8) {
        float4 wb = *(const float4*)&Wm2t[c1][k4];
        p1 = fmaf(hv.x, wb.x, p1); p1 = fmaf(hv.y, wb.y, p1);
        p1 = fmaf(hv.z, wb.z, p1); p1 = fmaf(hv.w, wb.w, p1);
      }
    }
    float* op = (float*)outp;
    op[(size_t)d * 40 + sub] = p0 + bm2[sub];
    if (sub < 8) op[(size_t)d * 40 + c1] = p1 + bm2[c1];
  }
}

}  // namespace

extern "C" void kernel_launch(void* const* d_in, const int* in_sizes, int n_in,
                              void* d_out, int out_size, void* d_ws, size_t ws_size,
                              hipStream_t stream) {
  const float* x   = (const float*)d_in[0];
  const void*  ei  = d_in[1];
  const float* W1  = (const float*)d_in[2];
  const float* b1  = (const float*)d_in[3];
  const float* W2  = (const float*)d_in[4];
  const float* b2  = (const float*)d_in[5];
  const float* Wm1 = (const float*)d_in[6];
  const float* bm1 = (const float*)d_in[7];
  const float* Wm2 = (const float*)d_in[8];
  const float* bm2 = (const float*)d_in[9];
  float* out = (float*)d_out;

  char* ws = (char*)d_ws;
  size_t off = 0;
  auto alloc = [&](size_t bytes) -> void* {
    void* p = ws + off;
    off = (off + bytes + 511) & ~(size_t)511;
    return p;
  };
  int*      bucketCnt = (int*)     alloc((size_t)NBUCK * 4);
  unsigned* tmp       = (unsigned*)alloc((size_t)NBUCK * CAP_RAW * 4);  // 6.4 MB
  int*      colA      = (int*)     alloc((size_t)NBUCK * CAP_COL * 4);  // 8.0 MB
  int*      rowS      = (int*)     alloc((size_t)N_NODES * 4);
  int*      rowE      = (int*)     alloc((size_t)N_NODES * 4);
  float*    dinv      = (float*)   alloc((size_t)N_NODES * 4);
  __half*   g1        = (__half*)  alloc((size_t)(N_NODES + 1) * 64 * 2);  // +1 zero row
  __half*   gB        = (__half*)  alloc((size_t)(N_NODES + 1) * 64 * 2);  // conv2 table
  (void)ws_size; (void)in_sizes; (void)n_in; (void)out_size;

  dim3 b256(256);
  int gGemm = (N_NODES + 127) / 128;
  int gAgg  = N_NODES / 8;  // 12500, exact
  int gBkt  = (N_EDGES + EPB_A - 1) / EPB_A;

  // preprocessing: 2-pass bucket sort -> padded CSR (shared by both convs)
  hipMemsetAsync(bucketCnt, 0, (size_t)NBUCK * 4, stream);
  bucket_kernel<<<gBkt, b256, 0, stream>>>(ei, bucketCnt, tmp);
  csr_kernel<<<NBUCK, b256, 0, stream>>>(tmp, bucketCnt, colA, rowS, rowE, dinv);

  // conv1 tables: g1 = (x@W1)*dinv (fp16); also zeroes both pad rows
  gemm_g_kernel<<<gGemm, b256, 0, stream>>>(x, W1, dinv, g1, gB, 0);

  // conv1 aggregate + fused conv2 gemm: gB = (relu(dinv*(self+sum)+b1)@W2)*dinv
  agg_fused<1><<<gAgg, b256, 0, stream>>>(g1, colA, rowS, rowE, dinv, b1, W2,
                                          nullptr, nullptr, nullptr, gB);

  // conv2 aggregate + fused MLP (both layers): out = relu((dinv*(self+sum)+b2)@Wm1+bm1)@Wm2+bm2
  agg_fused<2><<<gAgg, b256, 0, stream>>>(gB, colA, rowS, rowE, dinv, b2, Wm1,
                                          bm1, Wm2, bm2, out);
}

// Round 8
// 249.252 us; speedup vs baseline: 1.1095x; 1.1095x over previous
//
#include <hip/hip_runtime.h>
#include <hip/hip_bf16.h>
#include <hip/hip_fp16.h>

// GCN: h1 = relu(GCNConv(x,W1,b1)); h2 = GCNConv(h1,W2,b2);
//      h3 = relu(h2@Wm1+bm1); out = h3@Wm2+bm2
// R2: CSR-by-dst gather-reduce replaced scatter atomics (10x write amp).
// R4: 2-pass XCD-local bucket sort. R5: dinv folded into GEMM epilogue.
// R6/R8 FAILED: multi-phase LDS GEMM fusion -> spills. R7: fp16 g-tables.
// R9: 2-node/wave aggregate, 8-deep (255.8us). R13 FAILED: 4-deep (263us).
// R14: cleanup (253.7us). R15 FAILED (1071us): scatter-side LDS agg -- wave
//      count is the throughput term for the latency-bound gather.
// R16 FAILED (268.5us): perm + csr-128. R17 NEUTRAL (252.2us): depth 16.
// R18 WIN (249.0us): per-row 64x64 GEMM fused into aggregate epilogues
//      (adds work to idle VALU WITHOUT touching gather shape/occupancy).
// R19 FAILED (272.9us): b64 dual-row gathers -> LDS conflicts.
// R20 FAILED (269.5us): uint4 wide gathers; vmem 4x down yet slower.
//      Gather-loop restructures NEVER pay (R13/15/16/17/19/20).
// R21 FAILED (276.5us): MLP-tail fusion into agg2 -> LDS 29.2KB -> 5
//      blocks/CU (occ 50%), staging 26.4KB x 12500 blocks; agg2 100us.
//      csr-128 now 0-for-2 (R16, R21). Both reverted.
// R22: R18 verbatim EXCEPT aggregate blocks are 512 thr / 16 nodes
//      (grid 12500 -> 6250): halves per-CU Ws staging + block prologues;
//      resident waves/CU unchanged (4 blocks x 8 waves = 32 = R18's 8x4;
//      LDS 20.5KB x 4 = 82KB). Clean A/B on per-block overhead.

namespace {

constexpr int N_NODES = 100000;
constexpr int N_EDGES = 1000000;
constexpr int NBUCK = (N_NODES + 511) / 512;  // 196 buckets of 512 nodes
constexpr int CAP_RAW = 8192;   // raw edges/bucket (mean 5120, sd ~71)
constexpr int CAP_COL = 12288;  // pad-16 edges/bucket (mean ~8400, sd ~80)
constexpr int EPB_A = 2048;     // edges per passA block

// passA: partition edges into NBUCK buckets by dst>>9. word=(src<<9)|(dst&511).
// Per-block int32/int64 detection: sample 512 odd words of own range (int64
// high halves are all 0; int32 node ids ~surely not).
__global__ __launch_bounds__(256) void bucket_kernel(const void* __restrict__ ei,
                                                     int* __restrict__ bucketCnt,
                                                     unsigned* __restrict__ tmp) {
  __shared__ int hist[NBUCK];
  __shared__ int basePB[NBUCK];
  __shared__ int cur[NBUCK];
  __shared__ int sflag;
  int t = threadIdx.x;
  if (t < NBUCK) { hist[t] = 0; cur[t] = 0; }
  if (t == 0) sflag = 0;
  __syncthreads();

  int e0 = blockIdx.x * EPB_A;
  const unsigned* w = (const unsigned*)ei;
  unsigned any = 0;
#pragma unroll
  for (int s = 0; s < 2; s++) {
    int e = e0 + s * 256 + t;
    if (e < N_EDGES) any |= w[2 * e + 1];
  }
  if (any) sflag = 1;  // benign race, all writers store 1
  __syncthreads();
  int is32 = sflag;

  unsigned wreg[8];
  int breg[8];
#pragma unroll
  for (int k = 0; k < 8; k++) {
    int e = e0 + k * 256 + t;
    breg[k] = -1;
    if (e < N_EDGES) {
      int s, d;
      if (is32) {
        const int* p = (const int*)ei;
        s = p[e]; d = p[N_EDGES + e];
      } else {
        const long long* p = (const long long*)ei;
        s = (int)p[e]; d = (int)p[N_EDGES + e];
      }
      wreg[k] = ((unsigned)s << 9) | (unsigned)(d & 511);
      breg[k] = d >> 9;
      atomicAdd(&hist[breg[k]], 1);
    }
  }
  __syncthreads();
  if (t < NBUCK) basePB[t] = hist[t] ? atomicAdd(&bucketCnt[t], hist[t]) : 0;
  __syncthreads();
#pragma unroll
  for (int k = 0; k < 8; k++) {
    if (breg[k] >= 0) {
      int r = atomicAdd(&cur[breg[k]], 1);
      tmp[(size_t)breg[k] * CAP_RAW + basePB[breg[k]] + r] = wreg[k];
    }
  }
}

// passB: one block per bucket. LDS counting sort; rows padded to mult 16 with
// sentinel N_NODES (zero row); emit row_start/row_end + dinv.
__global__ __launch_bounds__(512) void csr_kernel(const unsigned* __restrict__ tmp,
                                                  const int* __restrict__ bucketCnt,
                                                  int* __restrict__ col,
                                                  int* __restrict__ row_start,
                                                  int* __restrict__ row_end,
                                                  float* __restrict__ dinv) {
  __shared__ int sc[512];
  __shared__ int hist[512];
  __shared__ unsigned stage[CAP_RAW];
  int b = blockIdx.x, t = threadIdx.x;
  int myCnt = bucketCnt[b];
  int baseT = b * CAP_RAW;
  int baseC = b * CAP_COL;

  hist[t] = 0;
  __syncthreads();
  for (int i = t; i < myCnt; i += 512) {
    unsigned w = tmp[(size_t)baseT + i];
    stage[i] = w;
    atomicAdd(&hist[w & 511u], 1);
  }
  __syncthreads();

  int deg = hist[t];
  int pdeg = (deg + 15) & ~15;  // pad rows to mult 16 (16-deep pipeline)
  sc[t] = pdeg;
  __syncthreads();
#pragma unroll
  for (int off = 1; off < 512; off <<= 1) {
    int u = (t >= off) ? sc[t - off] : 0;
    __syncthreads();
    sc[t] += u;
    __syncthreads();
  }
  int pexcl = sc[t] - pdeg;
  int d = b * 512 + t;
  if (d < N_NODES) {
    row_start[d] = baseC + pexcl;
    row_end[d] = baseC + pexcl + pdeg;
    dinv[d] = rsqrtf((float)deg + 1.0f);
  }
  __syncthreads();
  hist[t] = pexcl;
  __syncthreads();
  for (int i = t; i < myCnt; i += 512) {
    unsigned w = stage[i];
    int pos = atomicAdd(&hist[w & 511u], 1);
    col[baseC + pos] = (int)(w >> 9);
  }
  for (int j = deg; j < pdeg; j++) col[baseC + pexcl + j] = N_NODES;
}

__device__ inline uint4 pack_half8(const float* v) {
  __half2 h0 = __floats2half2_rn(v[0], v[1]);
  __half2 h1 = __floats2half2_rn(v[2], v[3]);
  __half2 h2 = __floats2half2_rn(v[4], v[5]);
  __half2 h3 = __floats2half2_rn(v[6], v[7]);
  uint4 u;
  u.x = *(unsigned*)&h0; u.y = *(unsigned*)&h1;
  u.z = *(unsigned*)&h2; u.w = *(unsigned*)&h3;
  return u;
}

// g[r] = (op(A[r])@W) * dinv[r], fp16 out, zero pad row N_NODES.
// 128 rows/block, 256 thr, thread = 4 rows x 8 cols. W staged in LDS.
__global__ __launch_bounds__(256) void gemm_g_kernel(const float* __restrict__ A,
                                                     const float* __restrict__ W,
                                                     const float* __restrict__ dinv,
                                                     __half* __restrict__ g,
                                                     __half* __restrict__ gpad2,
                                                     int reluIn) {
  __shared__ float Ws[64 * 64];
  int t = threadIdx.x;
  if (blockIdx.x == 0 && t < 32) {
    ((float*)(g + (size_t)N_NODES * 64))[t] = 0.f;  // pad row (this table)
    if (gpad2) ((float*)(gpad2 + (size_t)N_NODES * 64))[t] = 0.f;  // pad row (agg1 output table)
  }
  for (int i = t; i < 64 * 64 / 4; i += 256) ((float4*)Ws)[i] = ((const float4*)W)[i];
  __syncthreads();

  int rg = t >> 3, cg = t & 7;
  int r0 = blockIdx.x * 128 + rg * 4;
  int c0 = cg * 8;

  float acc[4][8];
#pragma unroll
  for (int i = 0; i < 4; i++)
#pragma unroll
    for (int j = 0; j < 8; j++) acc[i][j] = 0.f;

  const float4* A4 = (const float4*)A;
  for (int kk = 0; kk < 16; kk++) {
    float4 a[4];
#pragma unroll
    for (int i = 0; i < 4; i++) {
      int r = r0 + i;
      float4 v = (r < N_NODES) ? A4[(size_t)r * 16 + kk] : make_float4(0.f, 0.f, 0.f, 0.f);
      if (reluIn) {
        v.x = fmaxf(v.x, 0.f); v.y = fmaxf(v.y, 0.f);
        v.z = fmaxf(v.z, 0.f); v.w = fmaxf(v.w, 0.f);
      }
      a[i] = v;
    }
#pragma unroll
    for (int q = 0; q < 4; q++) {
      int k = kk * 4 + q;
      float w[8];
#pragma unroll
      for (int j = 0; j < 2; j++) *(float4*)&w[4 * j] = *(const float4*)&Ws[k * 64 + c0 + 4 * j];
#pragma unroll
      for (int i = 0; i < 4; i++) {
        float av = q == 0 ? a[i].x : q == 1 ? a[i].y : q == 2 ? a[i].z : a[i].w;
#pragma unroll
        for (int j = 0; j < 8; j++) acc[i][j] = fmaf(av, w[j], acc[i][j]);
      }
    }
  }
#pragma unroll
  for (int i = 0; i < 4; i++) {
    int r = r0 + i;
    if (r < N_NODES) {
      float s = dinv[r];
#pragma unroll
      for (int j = 0; j < 8; j++) acc[i][j] *= s;
      *(uint4*)(g + (size_t)r * 64 + c0) = pack_half8(acc[i]);
    }
  }
}

// Fused gather-aggregate + per-row 64x64 GEMM epilogue (R18 structure,
// R22: 512 thr / 16 nodes per block; per-lane code identical to R18).
// Gather: 2 nodes/wave (lanes 0-31 node d0, 32-63 node d1); lane covers 2
// feats as one half2 gather (one instr fetches TWO 128B rows); 16-deep
// pipeline; sentinel pad rows hit the L1-hot zero row.
// Epilogue: row h = dinv*(self+sum)+bconv staged in per-half-wave LDS slot
// (wave-synchronous); lane computes cols {2sub, 2sub+1} = h @ W from
// Ws[64*64] (b64 reads, 2-way alias = free; h reads broadcast).
// MODE 1 (conv1 -> conv2 g-table): relu(h) pre-GEMM, *dinv post, fp16 out.
// MODE 2 (conv2 -> MLP hidden):    no pre-relu, +bpost then relu, fp32 out.
template <int MODE>
__global__ __launch_bounds__(512) void agg_fused(const __half* __restrict__ g,
                                                 const int* __restrict__ col,
                                                 const int* __restrict__ row_start,
                                                 const int* __restrict__ row_end,
                                                 const float* __restrict__ dinv,
                                                 const float* __restrict__ bconv,
                                                 const float* __restrict__ W,
                                                 const float* __restrict__ bpost,
                                                 void* __restrict__ outp) {
  __shared__ float Ws[64 * 64];    // 16 KB
  __shared__ float rows[16][64];   // 4 KB, one row slot per half-wave
  int t = threadIdx.x;
  for (int i = t; i < 64 * 64 / 4; i += 512) ((float4*)Ws)[i] = ((const float4*)W)[i];
  __syncthreads();

  int wave = t >> 6;
  int lane = t & 63;
  int half = lane >> 5;
  int sub = lane & 31;
  int slot = t >> 5;  // half-wave id 0..15
  int d = blockIdx.x * 16 + wave * 2 + half;

  const __half2* g2 = (const __half2*)g;
  int e0 = row_start[d];
  int len = row_end[d] - e0;

  float2 a0 = __half22float2(g2[(size_t)d * 32 + sub]);  // self (dinv in g)
  float2 a1 = {0.f, 0.f}, a2 = {0.f, 0.f}, a3 = {0.f, 0.f};
  float2 a4 = {0.f, 0.f}, a5 = {0.f, 0.f}, a6 = {0.f, 0.f}, a7 = {0.f, 0.f};

  for (int i = 0; i < len; i += 16) {  // per-half-wave trip count (exec-mask divergence)
    int4 ca = *(const int4*)(col + e0 + i);
    int4 cb = *(const int4*)(col + e0 + i + 4);
    int4 cc = *(const int4*)(col + e0 + i + 8);
    int4 cd = *(const int4*)(col + e0 + i + 12);
    float2 h0 = __half22float2(g2[(size_t)ca.x * 32 + sub]);
    float2 h1 = __half22float2(g2[(size_t)ca.y * 32 + sub]);
    float2 h2 = __half22float2(g2[(size_t)ca.z * 32 + sub]);
    float2 h3 = __half22float2(g2[(size_t)ca.w * 32 + sub]);
    float2 h4 = __half22float2(g2[(size_t)cb.x * 32 + sub]);
    float2 h5 = __half22float2(g2[(size_t)cb.y * 32 + sub]);
    float2 h6 = __half22float2(g2[(size_t)cb.z * 32 + sub]);
    float2 h7 = __half22float2(g2[(size_t)cb.w * 32 + sub]);
    float2 h8 = __half22float2(g2[(size_t)cc.x * 32 + sub]);
    float2 h9 = __half22float2(g2[(size_t)cc.y * 32 + sub]);
    float2 hA = __half22float2(g2[(size_t)cc.z * 32 + sub]);
    float2 hB = __half22float2(g2[(size_t)cc.w * 32 + sub]);
    float2 hC = __half22float2(g2[(size_t)cd.x * 32 + sub]);
    float2 hD = __half22float2(g2[(size_t)cd.y * 32 + sub]);
    float2 hE = __half22float2(g2[(size_t)cd.z * 32 + sub]);
    float2 hF = __half22float2(g2[(size_t)cd.w * 32 + sub]);
    a0.x += h0.x; a0.y += h0.y; a1.x += h1.x; a1.y += h1.y;
    a2.x += h2.x; a2.y += h2.y; a3.x += h3.x; a3.y += h3.y;
    a4.x += h4.x; a4.y += h4.y; a5.x += h5.x; a5.y += h5.y;
    a6.x += h6.x; a6.y += h6.y; a7.x += h7.x; a7.y += h7.y;
    a0.x += h8.x; a0.y += h8.y; a1.x += h9.x; a1.y += h9.y;
    a2.x += hA.x; a2.y += hA.y; a3.x += hB.x; a3.y += hB.y;
    a4.x += hC.x; a4.y += hC.y; a5.x += hD.x; a5.y += hD.y;
    a6.x += hE.x; a6.y += hE.y; a7.x += hF.x; a7.y += hF.y;
  }
  float rx = ((a0.x + a1.x) + (a2.x + a3.x)) + ((a4.x + a5.x) + (a6.x + a7.x));
  float ry = ((a0.y + a1.y) + (a2.y + a3.y)) + ((a4.y + a5.y) + (a6.y + a7.y));
  float dv = dinv[d];
  float2 bv = ((const float2*)bconv)[sub];
  float hx = fmaf(rx, dv, bv.x);
  float hy = fmaf(ry, dv, bv.y);
  if (MODE == 1) { hx = fmaxf(hx, 0.f); hy = fmaxf(hy, 0.f); }

  // stage row in this half-wave's slot; wave-synchronous (single-instruction
  // write covers all lanes, subsequent reads ordered by lgkmcnt)
  *(float2*)&rows[slot][2 * sub] = make_float2(hx, hy);

  float o0 = 0.f, o1 = 0.f;
#pragma unroll 8
  for (int ks = 0; ks < 32; ks++) {
    float2 hv = *(const float2*)&rows[slot][2 * ks];           // broadcast
    float2 w0 = *(const float2*)&Ws[(2 * ks) * 64 + 2 * sub];  // 2-way bank (free)
    float2 w1 = *(const float2*)&Ws[(2 * ks + 1) * 64 + 2 * sub];
    o0 = fmaf(hv.x, w0.x, o0);
    o0 = fmaf(hv.y, w1.x, o0);
    o1 = fmaf(hv.x, w0.y, o1);
    o1 = fmaf(hv.y, w1.y, o1);
  }

  if (MODE == 1) {
    o0 *= dv; o1 *= dv;
    __half2 hh = __floats2half2_rn(o0, o1);
    ((__half2*)outp)[(size_t)d * 32 + sub] = hh;
  } else {
    float2 bp = ((const float2*)bpost)[sub];
    float2 o;
    o.x = fmaxf(o0 + bp.x, 0.f);
    o.y = fmaxf(o1 + bp.y, 0.f);
    ((float2*)outp)[(size_t)d * 32 + sub] = o;
  }
}

// fp32 GEMM for the MLP tail: C[n,F] = op(A[n,64])@W[64,F] (+bias)(relu).
// Single-phase only (see R6/R8 spill rule).
template <int F>
__global__ __launch_bounds__(256) void gemm_kernel(const float* __restrict__ A, const float* __restrict__ W,
                                                   const float* __restrict__ bias, float* __restrict__ C,
                                                   int n, int reluIn, int reluOut) {
  constexpr int CPT = F / 8;
  __shared__ float Ws[64 * F];
  int t = threadIdx.x;
  for (int i = t; i < 64 * F / 4; i += 256) ((float4*)Ws)[i] = ((const float4*)W)[i];
  __syncthreads();

  int rg = t >> 3, cg = t & 7;
  int r0 = blockIdx.x * 128 + rg * 4;
  int c0 = cg * CPT;

  float acc[4][CPT];
#pragma unroll
  for (int i = 0; i < 4; i++)
#pragma unroll
    for (int j = 0; j < CPT; j++) acc[i][j] = 0.f;

  const float4* A4 = (const float4*)A;
  for (int kk = 0; kk < 16; kk++) {
    float4 a[4];
#pragma unroll
    for (int i = 0; i < 4; i++) {
      int r = r0 + i;
      float4 v = (r < n) ? A4[(size_t)r * 16 + kk] : make_float4(0.f, 0.f, 0.f, 0.f);
      if (reluIn) {
        v.x = fmaxf(v.x, 0.f); v.y = fmaxf(v.y, 0.f);
        v.z = fmaxf(v.z, 0.f); v.w = fmaxf(v.w, 0.f);
      }
      a[i] = v;
    }
#pragma unroll
    for (int q = 0; q < 4; q++) {
      int k = kk * 4 + q;
      float w[CPT];
      if constexpr (CPT % 4 == 0) {
#pragma unroll
        for (int j = 0; j < CPT / 4; j++)
          *(float4*)&w[4 * j] = *(const float4*)&Ws[k * F + c0 + 4 * j];  // ds_read_b128
      } else {
#pragma unroll
        for (int j = 0; j < CPT; j++) w[j] = Ws[k * F + c0 + j];
      }
#pragma unroll
      for (int i = 0; i < 4; i++) {
        float av = q == 0 ? a[i].x : q == 1 ? a[i].y : q == 2 ? a[i].z : a[i].w;
#pragma unroll
        for (int j = 0; j < CPT; j++) acc[i][j] = fmaf(av, w[j], acc[i][j]);
      }
    }
  }

  float bv[CPT];
#pragma unroll
  for (int j = 0; j < CPT; j++) bv[j] = bias ? bias[c0 + j] : 0.f;
#pragma unroll
  for (int i = 0; i < 4; i++) {
    int r = r0 + i;
    if (r < n) {
      float* crow = C + (size_t)r * F + c0;
#pragma unroll
      for (int j = 0; j < CPT; j++) {
        float v = acc[i][j] + bv[j];
        if (reluOut) v = fmaxf(v, 0.f);
        crow[j] = v;
      }
    }
  }
}

}  // namespace

extern "C" void kernel_launch(void* const* d_in, const int* in_sizes, int n_in,
                              void* d_out, int out_size, void* d_ws, size_t ws_size,
                              hipStream_t stream) {
  const float* x   = (const float*)d_in[0];
  const void*  ei  = d_in[1];
  const float* W1  = (const float*)d_in[2];
  const float* b1  = (const float*)d_in[3];
  const float* W2  = (const float*)d_in[4];
  const float* b2  = (const float*)d_in[5];
  const float* Wm1 = (const float*)d_in[6];
  const float* bm1 = (const float*)d_in[7];
  const float* Wm2 = (const float*)d_in[8];
  const float* bm2 = (const float*)d_in[9];
  float* out = (float*)d_out;

  char* ws = (char*)d_ws;
  size_t off = 0;
  auto alloc = [&](size_t bytes) -> void* {
    void* p = ws + off;
    off = (off + bytes + 511) & ~(size_t)511;
    return p;
  };
  int*      bucketCnt = (int*)     alloc((size_t)NBUCK * 4);
  unsigned* tmp       = (unsigned*)alloc((size_t)NBUCK * CAP_RAW * 4);  // 6.4 MB
  int*      colA      = (int*)     alloc((size_t)NBUCK * CAP_COL * 4);  // 9.6 MB
  int*      rowS      = (int*)     alloc((size_t)N_NODES * 4);
  int*      rowE      = (int*)     alloc((size_t)N_NODES * 4);
  float*    dinv      = (float*)   alloc((size_t)N_NODES * 4);
  __half*   g1        = (__half*)  alloc((size_t)(N_NODES + 1) * 64 * 2);  // +1 zero row
  __half*   gB        = (__half*)  alloc((size_t)(N_NODES + 1) * 64 * 2);  // conv2 table
  float*    hA        = (float*)   alloc((size_t)N_NODES * 64 * 4);
  (void)ws_size; (void)in_sizes; (void)n_in; (void)out_size;

  dim3 b256(256);
  int gGemm = (N_NODES + 127) / 128;
  int gAgg  = N_NODES / 16;  // 6250, exact (512 thr / 16 nodes per block)
  int gBkt  = (N_EDGES + EPB_A - 1) / EPB_A;

  // preprocessing: 2-pass bucket sort -> padded CSR (shared by both convs)
  hipMemsetAsync(bucketCnt, 0, (size_t)NBUCK * 4, stream);
  bucket_kernel<<<gBkt, b256, 0, stream>>>(ei, bucketCnt, tmp);
  csr_kernel<<<NBUCK, dim3(512), 0, stream>>>(tmp, bucketCnt, colA, rowS, rowE, dinv);

  // conv1 tables: g1 = (x@W1)*dinv (fp16); also zeroes both pad rows
  gemm_g_kernel<<<gGemm, b256, 0, stream>>>(x, W1, dinv, g1, gB, 0);

  // conv1 aggregate + fused conv2 gemm: gB = (relu(dinv*(self+sum)+b1)@W2)*dinv
  agg_fused<1><<<gAgg, dim3(512), 0, stream>>>(g1, colA, rowS, rowE, dinv, b1, W2, nullptr, gB);

  // conv2 aggregate + fused MLP-1: hA = relu((dinv*(self+sum)+b2)@Wm1 + bm1)
  agg_fused<2><<<gAgg, dim3(512), 0, stream>>>(gB, colA, rowS, rowE, dinv, b2, Wm1, bm1, hA);

  // MLP tail: out = hA@Wm2+bm2
  gemm_kernel<40><<<gGemm, b256, 0, stream>>>(hA, Wm2, bm2, out, N_NODES, 0, 0);
}